// Round 1
// baseline (772.111 us; speedup 1.0000x reference)
//
#include <hip/hip_runtime.h>
#include <math.h>

#define B_SZ  4
#define T_SEQ 4096
#define D_IN  768
#define HS    64

// ---------------- Kernel A: QKV projection ----------------
// grid = (B*T)/ROWS_A blocks, 192 threads (3 waves: q-group, k-group, v-group)
#define ROWS_A 16
__global__ __launch_bounds__(192) void qkv_kernel(
    const float* __restrict__ x,
    const float* __restrict__ Wq, const float* __restrict__ Wk, const float* __restrict__ Wv,
    float* __restrict__ q, float* __restrict__ k, float* __restrict__ v)
{
    __shared__ __align__(16) float xs[ROWS_A][D_IN];   // 48 KB
    const long base_row = (long)blockIdx.x * ROWS_A;

    const float4* xg = (const float4*)(x + base_row * D_IN);
    float4* xl = (float4*)(&xs[0][0]);
    for (int i = threadIdx.x; i < ROWS_A * D_IN / 4; i += 192) xl[i] = xg[i];
    __syncthreads();

    const int m = threadIdx.x >> 6;   // 0:q 1:k 2:v
    const int h = threadIdx.x & 63;
    const float* W   = (m == 0) ? Wq : (m == 1) ? Wk : Wv;
    float*       outp = (m == 0) ? q  : (m == 1) ? k  : v;

    float acc[ROWS_A];
#pragma unroll
    for (int r = 0; r < ROWS_A; r++) acc[r] = 0.f;

    for (int d4 = 0; d4 < D_IN / 4; d4++) {
        const float w0 = W[(4*d4+0)*HS + h];   // coalesced across h
        const float w1 = W[(4*d4+1)*HS + h];
        const float w2 = W[(4*d4+2)*HS + h];
        const float w3 = W[(4*d4+3)*HS + h];
#pragma unroll
        for (int r = 0; r < ROWS_A; r++) {
            const float4 xv = *(const float4*)&xs[r][4*d4];  // uniform -> LDS broadcast
            acc[r] += xv.x*w0 + xv.y*w1 + xv.z*w2 + xv.w*w3;
        }
    }
#pragma unroll
    for (int r = 0; r < ROWS_A; r++) outp[(base_row + r) * HS + h] = acc[r];
}

// ---------------- Kernel B: causal flash attention ----------------
// grid = B*(T/TQ) = 256 blocks, 256 threads.
// lane = q-row (per-thread online softmax); the 4 waves split the key tiles
// (kt % 4 == w) with wave-private LDS K/V buffers, merged at the end.
#define TQ 64
#define KT 16
#define NW 4

__global__ __launch_bounds__(256) void attn_kernel(
    const float* __restrict__ q, const float* __restrict__ k, const float* __restrict__ v,
    float* __restrict__ out)
{
    // phase 1: K[NW][KT][HS] + V[NW][KT][HS] = 8192 floats
    // phase 2 (reuse): O2[NW][TQ][36] = 9216 floats
    __shared__ __align__(16) float smem[9216];
    __shared__ float ldsM[NW][TQ];
    __shared__ float ldsL[NW][TQ];

    const int tile = blockIdx.x;
    const int b    = tile / (T_SEQ / TQ);
    const int g    = tile % (T_SEQ / TQ);
    const int base = g * TQ;
    const int w    = threadIdx.x >> 6;
    const int lane = threadIdx.x & 63;
    const int t    = base + lane;          // q row owned by this lane

    const float* qb = q + (long)b * T_SEQ * HS;
    const float* kb = k + (long)b * T_SEQ * HS;
    const float* vb = v + (long)b * T_SEQ * HS;

    float qr[HS];
    {
        const float4* q4 = (const float4*)(qb + (long)t * HS);
#pragma unroll
        for (int i = 0; i < HS/4; i++) {
            const float4 tmp = q4[i];
            qr[4*i+0]=tmp.x; qr[4*i+1]=tmp.y; qr[4*i+2]=tmp.z; qr[4*i+3]=tmp.w;
        }
    }

    float mrun = -INFINITY, lrun = 0.f;
    float o[HS];
#pragma unroll
    for (int i = 0; i < HS; i++) o[i] = 0.f;

    float* Kw = smem + w * (KT*HS);
    float* Vw = smem + NW*KT*HS + w * (KT*HS);
    const int nkt = (base + TQ) / KT;      // = 4g+4, divisible by NW -> equal trips/wave

    for (int kt = w; kt < nkt; kt += NW) {
        const int k0 = kt * KT;
        {   // stage this wave's K/V chunk (contiguous 1024 floats each, coalesced)
            const float4* kg = (const float4*)(kb + (long)k0 * HS);
            const float4* vg = (const float4*)(vb + (long)k0 * HS);
            float4* kl = (float4*)Kw;
            float4* vl = (float4*)Vw;
#pragma unroll
            for (int i = 0; i < (KT*HS/4)/64; i++) {
                kl[lane + 64*i] = kg[lane + 64*i];
                vl[lane + 64*i] = vg[lane + 64*i];
            }
        }
        __syncthreads();   // orders LDS write->read (equal trip count on all waves)

        float s[KT];
        float tmax = -INFINITY;
#pragma unroll
        for (int j = 0; j < KT; j++) {
            float acc = 0.f;
#pragma unroll
            for (int i = 0; i < HS/4; i++) {
                const float4 kv = *(const float4*)&Kw[j*HS + 4*i];  // uniform -> broadcast
                acc += qr[4*i]*kv.x + qr[4*i+1]*kv.y + qr[4*i+2]*kv.z + qr[4*i+3]*kv.w;
            }
            s[j] = (k0 + j <= t) ? acc * 0.125f : -INFINITY;  // causal mask, scale=1/sqrt(64)
            tmax = fmaxf(tmax, s[j]);
        }

        if (tmax > -INFINITY) {            // lane has >=1 unmasked key in this chunk
            const float mnew  = fmaxf(mrun, tmax);
            const float alpha = __expf(mrun - mnew);   // mrun=-inf first time -> 0
            float psum = 0.f;
#pragma unroll
            for (int j = 0; j < KT; j++) { s[j] = __expf(s[j] - mnew); psum += s[j]; }
            lrun = lrun * alpha + psum;
#pragma unroll
            for (int i = 0; i < HS; i++) o[i] *= alpha;
#pragma unroll
            for (int j = 0; j < KT; j++) {
                const float p = s[j];
#pragma unroll
                for (int i = 0; i < HS/4; i++) {
                    const float4 vv = *(const float4*)&Vw[j*HS + 4*i];
                    o[4*i+0] += p*vv.x; o[4*i+1] += p*vv.y;
                    o[4*i+2] += p*vv.z; o[4*i+3] += p*vv.w;
                }
            }
            mrun = mnew;
        }
        __syncthreads();
    }

    // ---- merge the 4 key-split partials per q row ----
    ldsM[w][lane] = mrun;
    ldsL[w][lane] = lrun;

    float* O2 = smem;  // [NW][TQ][36], reuses K/V space
    float* outp = out + ((long)b * T_SEQ + base) * HS;

    for (int half = 0; half < 2; half++) {
        __syncthreads();   // all waves done with prior smem use
#pragma unroll
        for (int i = 0; i < 8; i++) {
            *(float4*)&O2[(w*TQ + lane)*36 + 4*i] =
                make_float4(o[half*32+4*i+0], o[half*32+4*i+1],
                            o[half*32+4*i+2], o[half*32+4*i+3]);
        }
        __syncthreads();
        for (int e = threadIdx.x; e < TQ*32; e += 256) {
            const int r  = e >> 5;
            const int hh = e & 31;
            const float M = fmaxf(fmaxf(ldsM[0][r], ldsM[1][r]),
                                  fmaxf(ldsM[2][r], ldsM[3][r]));
            float L = 0.f, val = 0.f;
#pragma unroll
            for (int ww = 0; ww < NW; ww++) {
                const float a = __expf(ldsM[ww][r] - M);  // -inf partial -> weight 0
                L   += ldsL[ww][r] * a;
                val += O2[(ww*TQ + r)*36 + hh] * a;
            }
            outp[r*HS + half*32 + hh] = val / L;   // coalesced
        }
    }
}

extern "C" void kernel_launch(void* const* d_in, const int* in_sizes, int n_in,
                              void* d_out, int out_size, void* d_ws, size_t ws_size,
                              hipStream_t stream) {
    const float* x  = (const float*)d_in[0];
    const float* Wq = (const float*)d_in[1];
    const float* Wk = (const float*)d_in[2];
    const float* Wv = (const float*)d_in[3];
    float* out = (float*)d_out;

    // workspace layout: q | k | v, each B*T*HS floats (12 MB total)
    const size_t nqkv = (size_t)B_SZ * T_SEQ * HS;
    float* q = (float*)d_ws;
    float* k = q + nqkv;
    float* v = k + nqkv;

    qkv_kernel<<<(B_SZ*T_SEQ)/ROWS_A, 192, 0, stream>>>(x, Wq, Wk, Wv, q, k, v);
    attn_kernel<<<B_SZ*(T_SEQ/TQ), 256, 0, stream>>>(q, k, v, out);
}

// Round 2
// 171.792 us; speedup vs baseline: 4.4945x; 4.4945x over previous
//
#include <hip/hip_runtime.h>
#include <math.h>

typedef __attribute__((ext_vector_type(8))) short short8;
typedef __attribute__((ext_vector_type(4))) float f32x4;
typedef unsigned short ushort_t;

#define TSEQ   4096
#define NBATCH 4
#define DMODEL 768
#define HS     64
#define NQT    (TSEQ/16)      // 256 q-tiles per batch

static __device__ __forceinline__ ushort_t f2bf(float f) {
  union { float f; unsigned u; } v; v.f = f;
  unsigned r = v.u + 0x7fffu + ((v.u >> 16) & 1u);   // RNE
  return (ushort_t)(r >> 16);
}

#define MFMA16(a,b,c) __builtin_amdgcn_mfma_f32_16x16x32_bf16((a),(b),(c),0,0,0)

// ---------------- W prep: Wt[n'=m*64+n][k] bf16 (transposed) ----------------
__global__ __launch_bounds__(256) void wprep(
    const float* __restrict__ Wq, const float* __restrict__ Wk,
    const float* __restrict__ Wv, ushort_t* __restrict__ Wt)
{
  const int np = blockIdx.x;            // 0..191
  const int m = np >> 6, n = np & 63;
  const float* W = (m == 0) ? Wq : (m == 1) ? Wk : Wv;
  for (int kk = threadIdx.x; kk < DMODEL; kk += 256)
    Wt[(size_t)np * DMODEL + kk] = f2bf(W[(size_t)kk * HS + n]);
}

// ---------------- QKV projection (MFMA): q,k [t][d] bf16, vT [b][d][t] bf16 --
// grid 256 blocks x 256 thr; M-tile 64, N=192; wave w owns n-tiles 3w..3w+2.
__global__ __launch_bounds__(256) void qkv_mfma(
    const float* __restrict__ x, const ushort_t* __restrict__ Wt,
    ushort_t* __restrict__ q, ushort_t* __restrict__ kO, ushort_t* __restrict__ vT)
{
  __shared__ __align__(16) ushort_t xs[64 * 32];    // x tile bf16, pitch 32
  __shared__ __align__(16) float vls[64 * 65];      // v transpose buffer (+1 pad)

  const int tid  = threadIdx.x;
  const int w    = tid >> 6, lane = tid & 63;
  const int l16  = lane & 15, quad = lane >> 4;
  const int Mbase = blockIdx.x * 64;
  const float* xg = x + (size_t)Mbase * DMODEL;

  f32x4 acc[4][3];
#pragma unroll
  for (int a = 0; a < 4; a++)
#pragma unroll
    for (int c = 0; c < 3; c++) acc[a][c] = (f32x4){0.f, 0.f, 0.f, 0.f};

  const int srow = tid >> 2;            // staging: 4 threads per x-row
  const int scol = (tid & 3) * 8;
  float4 ra = *(const float4*)(xg + (size_t)srow * DMODEL + scol);
  float4 rb = *(const float4*)(xg + (size_t)srow * DMODEL + scol + 4);

  for (int ks = 0; ks < DMODEL / 32; ks++) {
    __syncthreads();                    // previous iteration's reads done
    {
      short8 p;
      p[0]=f2bf(ra.x); p[1]=f2bf(ra.y); p[2]=f2bf(ra.z); p[3]=f2bf(ra.w);
      p[4]=f2bf(rb.x); p[5]=f2bf(rb.y); p[6]=f2bf(rb.z); p[7]=f2bf(rb.w);
      *(short8*)(xs + srow * 32 + scol) = p;
    }
    if (ks < DMODEL / 32 - 1) {         // prefetch next chunk (overlaps MFMA)
      ra = *(const float4*)(xg + (size_t)srow * DMODEL + (ks + 1) * 32 + scol);
      rb = *(const float4*)(xg + (size_t)srow * DMODEL + (ks + 1) * 32 + scol + 4);
    }
    __syncthreads();                    // xs ready
    short8 af[4];
#pragma unroll
    for (int mt = 0; mt < 4; mt++)
      af[mt] = *(const short8*)(xs + (mt * 16 + l16) * 32 + quad * 8);
#pragma unroll
    for (int ntl = 0; ntl < 3; ntl++) {
      const int np = (w * 3 + ntl) * 16 + l16;
      const short8 bf = *(const short8*)(Wt + (size_t)np * DMODEL + ks * 32 + quad * 8);
#pragma unroll
      for (int mt = 0; mt < 4; mt++) acc[mt][ntl] = MFMA16(af[mt], bf, acc[mt][ntl]);
    }
  }

  // epilogue: q (x0.125 folded), k direct bf16 stores; v via LDS transpose
#pragma unroll
  for (int ntl = 0; ntl < 3; ntl++) {
    const int nt  = w * 3 + ntl;
    const int mat = nt >> 2;            // 0=q 1=k 2=v (wave-uniform)
    const int nc0 = (nt & 3) * 16;
#pragma unroll
    for (int mt = 0; mt < 4; mt++) {
#pragma unroll
      for (int r = 0; r < 4; r++) {
        const float val = acc[mt][ntl][r];
        const int trow = Mbase + mt * 16 + quad * 4 + r;
        const int col  = nc0 + l16;
        if (mat == 0)      q [(size_t)trow * HS + col] = f2bf(val * 0.125f);
        else if (mat == 1) kO[(size_t)trow * HS + col] = f2bf(val);
        else               vls[(mt * 16 + quad * 4 + r) * 65 + col] = val;
      }
    }
  }
  __syncthreads();
  const int bb   = Mbase >> 12;
  const int tloc = Mbase & (TSEQ - 1);
#pragma unroll
  for (int it = 0; it < 16; it++) {
    const int d = it * 4 + w;
    const float val = vls[lane * 65 + d];
    vT[((size_t)bb * HS + d) * TSEQ + tloc + lane] = f2bf(val);
  }
}

// ---------------- causal flash attention (MFMA) ----------------
// grid B*NQT=1024 blocks (big q-tiles first), 256 thr. 16 q-rows per block;
// 4 waves split key tiles (Bc=32) with wave-private LDS; merge at end.
#define KP 72     // K LDS pitch (bf16)   [32][72]
#define VP 40     // Vt LDS pitch         [64][40]
#define PP 40     // P LDS pitch          [16][40]

__global__ __launch_bounds__(256) void attn_mfma(
    const ushort_t* __restrict__ q, const ushort_t* __restrict__ k,
    const ushort_t* __restrict__ vT, float* __restrict__ out)
{
  __shared__ __align__(16) ushort_t sK[4][32 * KP];
  __shared__ __align__(16) ushort_t sV[4][64 * VP];
  __shared__ __align__(16) ushort_t sP[4][16 * PP];
  __shared__ float sM[4][16];
  __shared__ float sL[4][16];

  const int idx   = blockIdx.x;
  const int b     = idx & 3;
  const int j     = (NQT - 1) - (idx >> 2);   // descending work order
  const int tbase = j * 16;
  const int w     = threadIdx.x >> 6;
  const int lane  = threadIdx.x & 63;
  const int l16   = lane & 15;
  const int quad  = lane >> 4;

  const ushort_t* qg = q  + ((size_t)b * TSEQ + tbase) * HS;
  const ushort_t* kg = k  + (size_t)b * TSEQ * HS;
  const ushort_t* vg = vT + (size_t)b * HS * TSEQ;

  ushort_t* Kw = sK[w];
  ushort_t* Vw = sV[w];
  ushort_t* Pw = sP[w];

  // Q fragments (q pre-scaled by 1/8 in producer)
  const short8 qf0 = *(const short8*)(qg + l16 * HS +      quad * 8);
  const short8 qf1 = *(const short8*)(qg + l16 * HS + 32 + quad * 8);

  f32x4 o0 = {0.f,0.f,0.f,0.f}, o1 = o0, o2 = o0, o3 = o0;
  float mrow[4] = {-INFINITY, -INFINITY, -INFINITY, -INFINITY};
  float lrow[4] = {0.f, 0.f, 0.f, 0.f};

  const int nkt = (j >> 1) + 1;               // 32-key tiles incl. diagonal
  for (int kt = w; kt < nkt; kt += 4) {
    const int k0 = kt * 32;
    // stage K [32 keys][64] and Vt [64 dims][32 keys] into padded LDS
#pragma unroll
    for (int i = 0; i < 4; i++) {
      const int c = i * 64 + lane;
      const int key = c >> 3, koff = (c & 7) * 8;
      *(short8*)(Kw + key * KP + koff) =
          *(const short8*)(kg + (size_t)(k0 + key) * HS + koff);
    }
#pragma unroll
    for (int i = 0; i < 4; i++) {
      const int c = i * 64 + lane;
      const int d = c >> 2, doff = (c & 3) * 8;
      *(short8*)(Vw + d * VP + doff) =
          *(const short8*)(vg + (size_t)d * TSEQ + k0 + doff);
    }
    // S = Q K^T   [16 rows x 32 keys]
    f32x4 s0 = {0.f,0.f,0.f,0.f}, s1 = s0;
    {
      short8 kf;
      kf = *(const short8*)(Kw + l16 * KP +        quad * 8); s0 = MFMA16(qf0, kf, s0);
      kf = *(const short8*)(Kw + l16 * KP + 32 +   quad * 8); s0 = MFMA16(qf1, kf, s0);
      kf = *(const short8*)(Kw + (l16+16) * KP +      quad * 8); s1 = MFMA16(qf0, kf, s1);
      kf = *(const short8*)(Kw + (l16+16) * KP + 32 + quad * 8); s1 = MFMA16(qf1, kf, s1);
    }
    // causal mask, only near diagonal (wave-uniform branch)
    if (k0 + 31 > tbase) {
      const int key0 = k0 + l16, key1 = key0 + 16;
#pragma unroll
      for (int r = 0; r < 4; r++) {
        const int row = tbase + quad * 4 + r;
        s0[r] = (key0 <= row) ? s0[r] : -INFINITY;
        s1[r] = (key1 <= row) ? s1[r] : -INFINITY;
      }
    }
    // online softmax (rows quad*4+r; reduce across the 16 lanes of the quad)
    float tm[4], al[4];
#pragma unroll
    for (int r = 0; r < 4; r++) tm[r] = fmaxf(s0[r], s1[r]);
#pragma unroll
    for (int mk = 1; mk < 16; mk <<= 1) {
#pragma unroll
      for (int r = 0; r < 4; r++) tm[r] = fmaxf(tm[r], __shfl_xor(tm[r], mk));
    }
#pragma unroll
    for (int r = 0; r < 4; r++) {
      const float mn = fmaxf(mrow[r], tm[r]);
      al[r] = __expf(mrow[r] - mn);           // -inf first time -> 0
      mrow[r] = mn;
      s0[r] = __expf(s0[r] - mn);             // masked -inf -> 0
      s1[r] = __expf(s1[r] - mn);
    }
    float ps[4];
#pragma unroll
    for (int r = 0; r < 4; r++) ps[r] = s0[r] + s1[r];
#pragma unroll
    for (int mk = 1; mk < 16; mk <<= 1) {
#pragma unroll
      for (int r = 0; r < 4; r++) ps[r] += __shfl_xor(ps[r], mk);
    }
#pragma unroll
    for (int r = 0; r < 4; r++) lrow[r] = lrow[r] * al[r] + ps[r];
    // P -> LDS (C-layout in, A-layout out)
#pragma unroll
    for (int r = 0; r < 4; r++) {
      Pw[(quad * 4 + r) * PP + l16]      = f2bf(s0[r]);
      Pw[(quad * 4 + r) * PP + l16 + 16] = f2bf(s1[r]);
    }
#pragma unroll
    for (int r = 0; r < 4; r++) {
      o0[r] *= al[r]; o1[r] *= al[r]; o2[r] *= al[r]; o3[r] *= al[r];
    }
    // O += P V
    const short8 pf = *(const short8*)(Pw + l16 * PP + quad * 8);
    short8 vf;
    vf = *(const short8*)(Vw + (l16     ) * VP + quad * 8); o0 = MFMA16(pf, vf, o0);
    vf = *(const short8*)(Vw + (l16 + 16) * VP + quad * 8); o1 = MFMA16(pf, vf, o1);
    vf = *(const short8*)(Vw + (l16 + 32) * VP + quad * 8); o2 = MFMA16(pf, vf, o2);
    vf = *(const short8*)(Vw + (l16 + 48) * VP + quad * 8); o3 = MFMA16(pf, vf, o3);
  }

  // merge 4 key-split partials per row
  if (l16 == 0) {
#pragma unroll
    for (int r = 0; r < 4; r++) {
      sM[w][quad * 4 + r] = mrow[r];
      sL[w][quad * 4 + r] = lrow[r];
    }
  }
  float* Ow = (float*)Kw;                 // 16x68 fp32 (4352 B) fits K region
#pragma unroll
  for (int r = 0; r < 4; r++) {
    Ow[(quad * 4 + r) * 68 + l16     ] = o0[r];
    Ow[(quad * 4 + r) * 68 + l16 + 16] = o1[r];
    Ow[(quad * 4 + r) * 68 + l16 + 32] = o2[r];
    Ow[(quad * 4 + r) * 68 + l16 + 48] = o3[r];
  }
  __syncthreads();

  const int row = threadIdx.x >> 4;       // 0..15
  const int d4  = threadIdx.x & 15;       // 0..15 -> 4 dims each
  const float M = fmaxf(fmaxf(sM[0][row], sM[1][row]),
                        fmaxf(sM[2][row], sM[3][row]));
  float den = 0.f;
  float4 num = make_float4(0.f, 0.f, 0.f, 0.f);
#pragma unroll
  for (int ww = 0; ww < 4; ww++) {
    const float a = __expf(sM[ww][row] - M);      // zero-trip wave: weight 0
    den += sL[ww][row] * a;
    const float* Op = (const float*)sK[ww];
    const float4 val = *(const float4*)(Op + row * 68 + d4 * 4);
    num.x += a * val.x; num.y += a * val.y; num.z += a * val.z; num.w += a * val.w;
  }
  const float inv = 1.f / den;
  *(float4*)(out + ((size_t)b * TSEQ + tbase + row) * HS + d4 * 4) =
      make_float4(num.x * inv, num.y * inv, num.z * inv, num.w * inv);
}

extern "C" void kernel_launch(void* const* d_in, const int* in_sizes, int n_in,
                              void* d_out, int out_size, void* d_ws, size_t ws_size,
                              hipStream_t stream) {
  const float* x  = (const float*)d_in[0];
  const float* Wq = (const float*)d_in[1];
  const float* Wk = (const float*)d_in[2];
  const float* Wv = (const float*)d_in[3];
  float* out = (float*)d_out;

  // ws: Wt (288 KB) | q (2 MB) | k (2 MB) | vT (2 MB)
  char* ws = (char*)d_ws;
  ushort_t* Wt = (ushort_t*)ws;
  ushort_t* qb = (ushort_t*)(ws + 294912);
  ushort_t* kb = (ushort_t*)(ws + 294912 + 2097152);
  ushort_t* vb = (ushort_t*)(ws + 294912 + 2 * 2097152);

  wprep<<<192, 256, 0, stream>>>(Wq, Wk, Wv, Wt);
  qkv_mfma<<<(NBATCH * TSEQ) / 64, 256, 0, stream>>>(x, Wt, qb, kb, vb);
  attn_mfma<<<NBATCH * NQT, 256, 0, stream>>>(qb, kb, vb, out);
}